// Round 4
// baseline (26.677 us; speedup 1.0000x reference)
//
#include <hip/hip_runtime.h>
#include <cstdint>

#define NN 1536
#define DD 60
#define HH 64
#define SEG 768               // adj elements per wave (half a row)
#define RPB 2                 // rows per block (4 waves: 2 rows x 2 halves)
#define ROW_BLOCKS (NN / RPB) // 768

// Kernel 1: Ap[i,h] = b1[h] + sum_d embed[i,d]*W1[d,h]   (row half, b1 folded)
//           Bp[i,h] =         sum_d embed[i,d]*W1[60+d,h] (col half)
__global__ __launch_bounds__(256) void prep_kernel(
    const float* __restrict__ embed, const float* __restrict__ W1,
    const float* __restrict__ b1, float* __restrict__ Ap,
    float* __restrict__ Bp) {
  int t = blockIdx.x * blockDim.x + threadIdx.x;
  int i = t >> 6, h = t & 63;
  if (i >= NN) return;
  float accA = b1[h], accB = 0.f;
  const float* er = embed + i * DD;
#pragma unroll
  for (int d = 0; d < DD; ++d) {
    float e = er[d];
    accA += e * W1[d * HH + h];
    accB += e * W1[(DD + d) * HH + h];
  }
  Ap[i * HH + h] = accA;
  Bp[i * HH + h] = accB;
}

__device__ __forceinline__ float sigmoidf_fast(float x) {
  return 1.f / (1.f + __expf(-x));
}

// Kernel 2: wave-autonomous fused row kernel. Each 64-lane wave owns half a
// row of adj/out: load segment -> shfl-scan compaction (NO atomics) into its
// own LDS jseg -> compute gates for its entries -> scatter into its own LDS
// row segment -> coalesced writeout. NO __syncthreads anywhere; waves never
// share LDS; within-wave LDS RAW is ordered by compiler lgkmcnt waits.
// adj nonzeros are exactly 1.0f (0/1 matrix), so the final adj* mul is free.
__global__ __launch_bounds__(256) void row_kernel(
    const float* __restrict__ Ap, const float* __restrict__ Bp,
    const float* __restrict__ W2, const float* __restrict__ b2,
    const float* __restrict__ adj, const float* __restrict__ noise,
    const int* __restrict__ tmp, float* __restrict__ out) {
  __shared__ unsigned short jseg_all[4 * SEG];  // 6 KB
  __shared__ float rowseg_all[4 * SEG];         // 12 KB

  const int tid = threadIdx.x;
  const int lane = tid & 63;
  const int w = tid >> 6;     // wave 0..3
  const int r = w >> 1;       // row within block
  const int half = w & 1;     // half of the row
  const int i = blockIdx.x * RPB + r;
  const int colbase = half * SEG;

  unsigned short* jl = jseg_all + w * SEG;
  float* rb = rowseg_all + w * SEG;

  // load adj segment: 3 coalesced float4 per lane
  const float4* a4 = (const float4*)(adj + i * NN + colbase);
  float4 v0 = a4[0 * 64 + lane];
  float4 v1 = a4[1 * 64 + lane];
  float4 v2 = a4[2 * 64 + lane];

  // zero own LDS row segment
  float4* rb4 = (float4*)rb;
  float4 z = make_float4(0.f, 0.f, 0.f, 0.f);
  rb4[0 * 64 + lane] = z;
  rb4[1 * 64 + lane] = z;
  rb4[2 * 64 + lane] = z;

  // 12-bit nonzero mask; bit b: chunk=b>>2, elem=b&3,
  // local j = (chunk*64+lane)*4 + elem
  unsigned mask = 0;
  mask |= (v0.x != 0.f) ? 0x001u : 0u;
  mask |= (v0.y != 0.f) ? 0x002u : 0u;
  mask |= (v0.z != 0.f) ? 0x004u : 0u;
  mask |= (v0.w != 0.f) ? 0x008u : 0u;
  mask |= (v1.x != 0.f) ? 0x010u : 0u;
  mask |= (v1.y != 0.f) ? 0x020u : 0u;
  mask |= (v1.z != 0.f) ? 0x040u : 0u;
  mask |= (v1.w != 0.f) ? 0x080u : 0u;
  mask |= (v2.x != 0.f) ? 0x100u : 0u;
  mask |= (v2.y != 0.f) ? 0x200u : 0u;
  mask |= (v2.z != 0.f) ? 0x400u : 0u;
  mask |= (v2.w != 0.f) ? 0x800u : 0u;

  int c = __popc(mask);
  // wave inclusive scan
  int incl = c;
#pragma unroll
  for (int off = 1; off < 64; off <<= 1) {
    int t = __shfl_up(incl, off, 64);
    if (lane >= off) incl += t;
  }
  int o = incl - c;                 // exclusive offset
  int nw = __shfl(incl, 63, 64);    // wave total

  // write compacted local-j list (order irrelevant; scatter by j later)
  unsigned mm = mask;
  while (mm) {
    int b = __ffs((int)mm) - 1;
    mm &= mm - 1;
    jl[o++] = (unsigned short)(((b >> 2) * 64 + lane) * 4 + (b & 3));
  }

  const float invb = 1.f / (float)(*tmp);
  const float bb = b2[0];
  const float4* Ai4 = (const float4*)(Ap + i * HH);
  const float4* Bi4 = (const float4*)(Bp + i * HH);
  const float4* W4 = (const float4*)W2;

  for (int t = lane; t < nw; t += 64) {
    int jloc = (int)jl[t];
    int j = colbase + jloc;
    const float4* Aj4 = (const float4*)(Ap + j * HH);
    const float4* Bj4 = (const float4*)(Bp + j * HH);
    float la_ij = bb, la_ji = bb;
#pragma unroll
    for (int q = 0; q < HH / 4; ++q) {
      float4 ai = Ai4[q], bi = Bi4[q], aj = Aj4[q], bj = Bj4[q], wv = W4[q];
      la_ij += fmaxf(ai.x + bj.x, 0.f) * wv.x + fmaxf(ai.y + bj.y, 0.f) * wv.y +
               fmaxf(ai.z + bj.z, 0.f) * wv.z + fmaxf(ai.w + bj.w, 0.f) * wv.w;
      la_ji += fmaxf(aj.x + bi.x, 0.f) * wv.x + fmaxf(aj.y + bi.y, 0.f) * wv.y +
               fmaxf(aj.z + bi.z, 0.f) * wv.z + fmaxf(aj.w + bi.w, 0.f) * wv.w;
    }
    float u1 = noise[i * NN + j];
    float u2 = noise[j * NN + i];
    float lg1 = __logf(u1) - __logf(1.f - u1);
    float lg2 = __logf(u2) - __logf(1.f - u2);
    float g1 = sigmoidf_fast((lg1 + la_ij) * invb);
    float g2 = sigmoidf_fast((lg2 + la_ji) * invb);
    rb[jloc] = 0.5f * (g1 + g2);  // adj nonzero == 1.0 exactly
  }

  // coalesced writeout of own segment (wave-converged; lgkmcnt orders LDS)
  float4* o4 = (float4*)(out + i * NN + colbase);
  o4[0 * 64 + lane] = rb4[0 * 64 + lane];
  o4[1 * 64 + lane] = rb4[1 * 64 + lane];
  o4[2 * 64 + lane] = rb4[2 * 64 + lane];
}

extern "C" void kernel_launch(void* const* d_in, const int* in_sizes, int n_in,
                              void* d_out, int out_size, void* d_ws,
                              size_t ws_size, hipStream_t stream) {
  const float* embed = (const float*)d_in[0];
  const float* W1 = (const float*)d_in[1];
  const float* b1 = (const float*)d_in[2];
  const float* W2 = (const float*)d_in[3];
  const float* b2 = (const float*)d_in[4];
  const float* adj = (const float*)d_in[5];
  const float* noise = (const float*)d_in[6];
  const int* tmp = (const int*)d_in[7];
  float* out = (float*)d_out;

  char* ws = (char*)d_ws;
  float* Ap = (float*)ws;                  // N*H floats
  float* Bp = (float*)(ws + NN * HH * 4);  // N*H floats

  hipLaunchKernelGGL(prep_kernel, dim3(NN * HH / 256), dim3(256), 0, stream,
                     embed, W1, b1, Ap, Bp);
  hipLaunchKernelGGL(row_kernel, dim3(ROW_BLOCKS), dim3(256), 0, stream, Ap,
                     Bp, W2, b2, adj, noise, tmp, out);
}

// Round 5
// 19.725 us; speedup vs baseline: 1.3524x; 1.3524x over previous
//
#include <hip/hip_runtime.h>
#include <hip/hip_fp16.h>
#include <cstdint>

#define NN 1536
#define DD 60
#define HH 64
#define RPB 2                 // rows per block
#define ROW_BLOCKS (NN / RPB) // 768

// prep: ABp[i][h] = half2( A[i,h]+b1[h] , B[i,h] )
//   A = embed @ W1[:60], B = embed @ W1[60:]. One contiguous 256B row per i.
__global__ __launch_bounds__(256) void prep_kernel(
    const float* __restrict__ embed, const float* __restrict__ W1,
    const float* __restrict__ b1, __half2* __restrict__ ABp) {
  int t = blockIdx.x * blockDim.x + threadIdx.x;
  int i = t >> 6, h = t & 63;
  float accA = b1[h], accB = 0.f;
  const float* er = embed + i * DD;
#pragma unroll
  for (int d = 0; d < DD; ++d) {
    float e = er[d];
    accA += e * W1[d * HH + h];
    accB += e * W1[(DD + d) * HH + h];
  }
  ABp[i * HH + h] = __floats2half2_rn(accA, accB);
}

// row kernel: block owns RPB rows. adj load -> wave-scan compaction (one LDS
// atomic per wave) -> block-strided gate compute with packed 256B AB gathers
// -> LDS rowbuf -> coalesced row writeout. adj nonzeros are exactly 1.0f.
__global__ __launch_bounds__(256) void row_kernel(
    const __half2* __restrict__ ABp, const float* __restrict__ W2,
    const float* __restrict__ b2, const float* __restrict__ adj,
    const float* __restrict__ noise, const int* __restrict__ tmp,
    float* __restrict__ out) {
  __shared__ float rowbuf[RPB * NN];                   // 12 KB
  __shared__ float w2L[HH];                            // 256 B
  __shared__ __align__(16) __half2 ABL[RPB * HH];      // 512 B
  __shared__ unsigned short jlist[RPB * NN];           // 6 KB
  __shared__ int njtot;

  const int tid = threadIdx.x;
  const int lane = tid & 63;
  const int i0 = blockIdx.x * RPB;

  // issue adj row loads early (3 coalesced float4 per thread)
  const float4* a4 = (const float4*)(adj + i0 * NN);
  float4 v0 = a4[tid + 0 * 256];
  float4 v1 = a4[tid + 1 * 256];
  float4 v2 = a4[tid + 2 * 256];

  if (tid < HH) w2L[tid] = W2[tid];
  if (tid >= 64 && tid < 64 + RPB * HH) {
    int x = tid - 64;
    ABL[x] = ABp[i0 * HH + x];
  }
  if (tid == 192) njtot = 0;

  // zero rowbuf
  float4* rb4 = (float4*)rowbuf;
  float4 z = make_float4(0.f, 0.f, 0.f, 0.f);
  rb4[tid + 0 * 256] = z;
  rb4[tid + 1 * 256] = z;
  rb4[tid + 2 * 256] = z;

  __syncthreads();

  // nonzero mask: bit b -> chunk=b>>2, elem=b&3
  unsigned mask = 0;
  mask |= (v0.x != 0.f) ? 0x001u : 0u;
  mask |= (v0.y != 0.f) ? 0x002u : 0u;
  mask |= (v0.z != 0.f) ? 0x004u : 0u;
  mask |= (v0.w != 0.f) ? 0x008u : 0u;
  mask |= (v1.x != 0.f) ? 0x010u : 0u;
  mask |= (v1.y != 0.f) ? 0x020u : 0u;
  mask |= (v1.z != 0.f) ? 0x040u : 0u;
  mask |= (v1.w != 0.f) ? 0x080u : 0u;
  mask |= (v2.x != 0.f) ? 0x100u : 0u;
  mask |= (v2.y != 0.f) ? 0x200u : 0u;
  mask |= (v2.z != 0.f) ? 0x400u : 0u;
  mask |= (v2.w != 0.f) ? 0x800u : 0u;

  int c = __popc(mask);
  int incl = c;
#pragma unroll
  for (int off = 1; off < 64; off <<= 1) {
    int t = __shfl_up(incl, off, 64);
    if (lane >= off) incl += t;
  }
  int wb = 0;
  if (lane == 63) wb = atomicAdd(&njtot, incl);  // one atomic per wave
  wb = __shfl(wb, 63, 64);
  int o = wb + incl - c;

  unsigned mm = mask;
  while (mm) {
    int b = __ffs((int)mm) - 1;
    mm &= mm - 1;
    int flat = (tid + (b >> 2) * 256) * 4 + (b & 3);
    int r = flat / NN;
    int j = flat - r * NN;
    jlist[o++] = (unsigned short)((r << 11) | j);
  }

  __syncthreads();

  const int n = njtot;
  const float invb = 1.f / (float)(*tmp);
  const float bb = b2[0];
  for (int t = tid; t < n; t += 256) {
    unsigned e = jlist[t];
    int r = (int)(e >> 11);
    int j = (int)(e & 2047u);
    int i = i0 + r;
    const float4* G = (const float4*)(ABp + j * HH);  // 256B contiguous
    const float4* L = (const float4*)(ABL + r * HH);  // LDS, broadcast
    float la_ij = bb, la_ji = bb;
#pragma unroll
    for (int q = 0; q < 16; ++q) {
      float4 g = G[q];
      float4 l = L[q];
      const __half2* gh = (const __half2*)&g;
      const __half2* lh = (const __half2*)&l;
#pragma unroll
      for (int s = 0; s < 4; ++s) {
        float2 gf = __half22float2(gh[s]);  // (A_j, B_j)
        float2 lf = __half22float2(lh[s]);  // (A_i, B_i)
        float w = w2L[4 * q + s];
        la_ij += fmaxf(lf.x + gf.y, 0.f) * w;
        la_ji += fmaxf(gf.x + lf.y, 0.f) * w;
      }
    }
    float u1 = noise[i * NN + j];
    float u2 = noise[j * NN + i];
    float lg1 = __logf(u1) - __logf(1.f - u1);
    float lg2 = __logf(u2) - __logf(1.f - u2);
    float g1 = 1.f / (1.f + __expf(-(lg1 + la_ij) * invb));
    float g2 = 1.f / (1.f + __expf(-(lg2 + la_ji) * invb));
    rowbuf[r * NN + j] = 0.5f * (g1 + g2);  // adj nonzero == 1.0 exactly
  }

  __syncthreads();

  float4* o4 = (float4*)(out + i0 * NN);
  o4[tid + 0 * 256] = rb4[tid + 0 * 256];
  o4[tid + 1 * 256] = rb4[tid + 1 * 256];
  o4[tid + 2 * 256] = rb4[tid + 2 * 256];
}

extern "C" void kernel_launch(void* const* d_in, const int* in_sizes, int n_in,
                              void* d_out, int out_size, void* d_ws,
                              size_t ws_size, hipStream_t stream) {
  const float* embed = (const float*)d_in[0];
  const float* W1 = (const float*)d_in[1];
  const float* b1 = (const float*)d_in[2];
  const float* W2 = (const float*)d_in[3];
  const float* b2 = (const float*)d_in[4];
  const float* adj = (const float*)d_in[5];
  const float* noise = (const float*)d_in[6];
  const int* tmp = (const int*)d_in[7];
  float* out = (float*)d_out;

  __half2* ABp = (__half2*)d_ws;  // NN*HH half2 = 384 KB

  hipLaunchKernelGGL(prep_kernel, dim3(NN * HH / 256), dim3(256), 0, stream,
                     embed, W1, b1, ABp);
  hipLaunchKernelGGL(row_kernel, dim3(ROW_BLOCKS), dim3(256), 0, stream, ABp,
                     W2, b2, adj, noise, tmp, out);
}